// Round 4
// baseline (297.282 us; speedup 1.0000x reference)
//
#include <hip/hip_runtime.h>
#include <math.h>

#define B 16
#define L 512
#define HID 768
#define HEADS 12
#define M 4
#define EMB 768
#define BLK 8
#define NER 6
#define NCLS 97
#define CAT (2*HID + NER)   // 1542
#define EB (EMB*BLK)        // 6144
#define NCH 16              // l-chunks for rs
#define LC (L/NCH)          // 32
#define ISCALE (1.f/(M*M*HEADS))

// ---------------------------------------------------------------------------
// K1: grid (B, HEADS), 512 thr. Per-head attention partial product
//     pp[b][h][l] = (sum_m A[b,h,s0m,l]) * (sum_m A[b,h,s1m,l])  (unscaled)
//     plus per-(b,h) sum Zp[b][h] (block reduce) so k_rs never re-reduces L.
//     Side jobs: h<2 -> ent_emb (logsumexp, e=h); h==2 -> zero rs.
// ---------------------------------------------------------------------------
__global__ void k_att(const float* __restrict__ att, const float* __restrict__ seq,
                      const int* __restrict__ epos,
                      float* __restrict__ pp, float* __restrict__ Zp,
                      float* __restrict__ ent, float* __restrict__ rs) {
    int b = blockIdx.x, h = blockIdx.y;
    __shared__ int ss[2][M];
    if (threadIdx.x < 2*M) {
        int e = threadIdx.x >> 2, m = threadIdx.x & 3;
        ss[e][m] = epos[(b*2+e)*M + m] + 1;
    }
    __syncthreads();

    int l = threadIdx.x;   // 512 threads = L
    const float* ah = att + ((size_t)b*HEADS + h)*L*L;
    float a0 = 0.f, a1 = 0.f;
    #pragma unroll
    for (int m = 0; m < M; ++m) {
        a0 += ah[(size_t)ss[0][m]*L + l];
        a1 += ah[(size_t)ss[1][m]*L + l];
    }
    float v = a0*a1;
    pp[((size_t)b*HEADS + h)*L + l] = v;

    // block-reduce v -> Zp[b][h]
    float r = v;
    for (int off = 32; off; off >>= 1) r += __shfl_down(r, off);
    __shared__ float wsum[8];
    int wid = threadIdx.x >> 6, lane = threadIdx.x & 63;
    if (lane == 0) wsum[wid] = r;
    __syncthreads();
    if (threadIdx.x == 0) {
        float t = 0.f;
        #pragma unroll
        for (int i = 0; i < 8; ++i) t += wsum[i];
        Zp[b*HEADS + h] = t;
    }

    if (h < 2) {
        // ent_emb for entity e=h: logsumexp over M mention rows
        const float* base = seq + (size_t)b*L*HID;
        for (int d = threadIdx.x; d < HID; d += 512) {
            float v0 = base[(size_t)ss[h][0]*HID + d];
            float v1 = base[(size_t)ss[h][1]*HID + d];
            float v2 = base[(size_t)ss[h][2]*HID + d];
            float v3 = base[(size_t)ss[h][3]*HID + d];
            float mx = fmaxf(fmaxf(v0, v1), fmaxf(v2, v3));
            float s = expf(v0-mx) + expf(v1-mx) + expf(v2-mx) + expf(v3-mx);
            ent[((size_t)h*B + b)*HID + d] = mx + logf(s);
        }
    } else if (h == 2) {
        for (int d = threadIdx.x; d < HID; d += 512) rs[b*HID + d] = 0.f;
    }
}

// ---------------------------------------------------------------------------
// K2: grid (B, NCH), 192 thr. Build this chunk's 32 normalized weights from
//     pp + Zp (L2-hot), then accumulate rs partials with float4 loads;
//     atomicAdd into rs[b][d].
// ---------------------------------------------------------------------------
__launch_bounds__(192)
__global__ void k_rs(const float* __restrict__ seq, const float* __restrict__ pp,
                     const float* __restrict__ Zp, float* __restrict__ rs) {
    int b = blockIdx.x, ch = blockIdx.y;
    __shared__ float sw[LC];
    if (threadIdx.x < LC) {
        float Z = 0.f;
        #pragma unroll
        for (int h = 0; h < HEADS; ++h) Z += Zp[b*HEADS + h];
        float inv = ISCALE / (Z*ISCALE + 1e-5f);
        int l = ch*LC + threadIdx.x;
        float r = 0.f;
        #pragma unroll
        for (int h = 0; h < HEADS; ++h) r += pp[((size_t)b*HEADS + h)*L + l];
        sw[threadIdx.x] = r * inv;
    }
    __syncthreads();

    const float4* sp = (const float4*)(seq + (size_t)b*L*HID + (size_t)ch*LC*HID);
    float4 acc = make_float4(0.f, 0.f, 0.f, 0.f);
    #pragma unroll 8
    for (int i = 0; i < LC; ++i) {
        float w = sw[i];
        float4 v = sp[i*(HID/4) + threadIdx.x];
        acc.x += v.x*w; acc.y += v.y*w; acc.z += v.z*w; acc.w += v.w*w;
    }
    float* rp = rs + b*HID + threadIdx.x*4;
    atomicAdd(rp+0, acc.x);
    atomicAdd(rp+1, acc.y);
    atomicAdd(rp+2, acc.z);
    atomicAdd(rp+3, acc.w);
}

// ---------------------------------------------------------------------------
// K3: hs2/ts2 = tanh([ent_e; rs; ner] @ W^T + b). Grid (EMB/8, 2, 2).
//     Activations transposed in LDS as actA/actB[k][4] so the 8-batch inner
//     read is 2 ds_read_b128 per k. 49 KB LDS -> 3 blocks/CU.
// ---------------------------------------------------------------------------
__launch_bounds__(512)
__global__ void k_proj(const float* __restrict__ Wh, const float* __restrict__ bh,
                       const float* __restrict__ Wt, const float* __restrict__ bt,
                       const float* __restrict__ ent, const float* __restrict__ rs,
                       const float* __restrict__ hner, const float* __restrict__ tner,
                       float* __restrict__ out) {
    int t = blockIdx.y, zh = blockIdx.z;
    __shared__ float actA[CAT*4];   // batches zh*8 + 0..3
    __shared__ float actB[CAT*4];   // batches zh*8 + 4..7
    const float* e0  = ent + (size_t)t*B*HID;
    const float* ner = t ? tner : hner;
    for (int idx = threadIdx.x; idx < CAT*8; idx += 512) {
        int k = idx >> 3, bi = idx & 7;
        int gb = zh*8 + bi;
        float v;
        if (k < HID)            v = e0[gb*HID + k];
        else if (k < 2*HID)     v = rs[gb*HID + (k - HID)];
        else                    v = ner[gb*NER + (k - 2*HID)];
        if (bi < 4) actA[k*4 + bi] = v; else actB[k*4 + bi - 4] = v;
    }
    __syncthreads();

    int wid = threadIdx.x >> 6, lane = threadIdx.x & 63;
    int j = blockIdx.x*8 + wid;
    const float* wrow = (t ? Wt : Wh) + (size_t)j*CAT;
    float acc[8];
    #pragma unroll
    for (int b = 0; b < 8; ++b) acc[b] = 0.f;
    for (int i = 0; i < 25; ++i) {
        int k = i*64 + lane;
        if (k < CAT) {
            float w = wrow[k];
            float4 a = *(const float4*)&actA[k*4];
            float4 c = *(const float4*)&actB[k*4];
            acc[0] += w*a.x; acc[1] += w*a.y; acc[2] += w*a.z; acc[3] += w*a.w;
            acc[4] += w*c.x; acc[5] += w*c.y; acc[6] += w*c.z; acc[7] += w*c.w;
        }
    }
    for (int off = 32; off; off >>= 1)
        #pragma unroll
        for (int b = 0; b < 8; ++b) acc[b] += __shfl_down(acc[b], off);
    if (lane == 0) {
        float bj = (t ? bt : bh)[j];
        #pragma unroll
        for (int b = 0; b < 8; ++b)
            out[((size_t)t*B + zh*8 + b)*EMB + j] = tanhf(acc[b] + bj);
    }
}

// ---------------------------------------------------------------------------
// K4: materialize bl. Grid (B,3) x 512 thr = exactly one float4 per thread.
// ---------------------------------------------------------------------------
__global__ void k_bl(const float* __restrict__ proj, float* __restrict__ bl) {
    int b = blockIdx.x;
    int i4 = blockIdx.y*512 + threadIdx.x;      // < EB/4 = 1536
    const float* ph = proj + (size_t)b*EMB;
    const float* pt = proj + (size_t)B*EMB + (size_t)b*EMB;
    int k = i4*4;
    int g = k >> 6, r = (k >> 3) & 7, c0 = k & 7;   // c0 in {0,4}
    float pr = ph[g*8 + r];
    float4 q = *(const float4*)(pt + g*8 + c0);
    ((float4*)(bl + (size_t)b*EB))[i4] = make_float4(pr*q.x, pr*q.y, pr*q.z, pr*q.w);
}

// ---------------------------------------------------------------------------
// K5: logits = bl @ Wb^T + bb. One block per class, float4 dot, all 16
//     batches in registers (Wb read once from HBM; bl L2-hot).
// ---------------------------------------------------------------------------
__launch_bounds__(512)
__global__ void k_logits(const float* __restrict__ Wb, const float* __restrict__ bb,
                         const float* __restrict__ bl, float* __restrict__ out) {
    int c = blockIdx.x;
    const float4* wr = (const float4*)(Wb + (size_t)c*EB);
    float acc[B];
    #pragma unroll
    for (int b = 0; b < B; ++b) acc[b] = 0.f;
    for (int i = threadIdx.x; i < EB/4; i += 512) {   // 3 iters
        float4 w = wr[i];
        #pragma unroll
        for (int b = 0; b < B; ++b) {
            float4 v = ((const float4*)(bl + (size_t)b*EB))[i];
            acc[b] += w.x*v.x + w.y*v.y + w.z*v.z + w.w*v.w;
        }
    }
    int wid = threadIdx.x >> 6, lane = threadIdx.x & 63;
    for (int off = 32; off; off >>= 1)
        #pragma unroll
        for (int b = 0; b < B; ++b) acc[b] += __shfl_down(acc[b], off);
    __shared__ float partl[8][B];
    if (lane == 0)
        #pragma unroll
        for (int b = 0; b < B; ++b) partl[wid][b] = acc[b];
    __syncthreads();
    if (threadIdx.x < B) {
        int b = threadIdx.x;
        float s = 0.f;
        #pragma unroll
        for (int w = 0; w < 8; ++w) s += partl[w][b];
        out[b*NCLS + c] = s + bb[c];
    }
}

extern "C" void kernel_launch(void* const* d_in, const int* in_sizes, int n_in,
                              void* d_out, int out_size, void* d_ws, size_t ws_size,
                              hipStream_t stream) {
    const float* seq  = (const float*)d_in[0];
    const float* att  = (const float*)d_in[1];
    const int*   epos = (const int*)  d_in[2];
    const float* hner = (const float*)d_in[3];
    const float* tner = (const float*)d_in[4];
    const float* Wh   = (const float*)d_in[5];
    const float* bh   = (const float*)d_in[6];
    const float* Wt   = (const float*)d_in[7];
    const float* bt   = (const float*)d_in[8];
    const float* Wb   = (const float*)d_in[9];
    const float* bb   = (const float*)d_in[10];
    float* out = (float*)d_out;

    // ws (floats): pp[B*HEADS*L] | Zp[B*HEADS] | ent[2*B*HID] | rs[B*HID] |
    //              proj[2*B*EMB] | bl[B*EB]
    float* ws   = (float*)d_ws;
    float* pp   = ws;
    float* Zp   = pp   + (size_t)B*HEADS*L;
    float* ent  = Zp   + B*HEADS;
    float* rs   = ent  + 2*B*HID;
    float* proj = rs   + B*HID;
    float* bl   = proj + 2*B*EMB;

    k_att   <<<dim3(B, HEADS),    512, 0, stream>>>(att, seq, epos, pp, Zp, ent, rs);
    k_rs    <<<dim3(B, NCH),      192, 0, stream>>>(seq, pp, Zp, rs);
    k_proj  <<<dim3(EMB/8, 2, 2), 512, 0, stream>>>(Wh, bh, Wt, bt, ent, rs, hner, tner, proj);
    k_bl    <<<dim3(B, 3),        512, 0, stream>>>(proj, bl);
    k_logits<<<dim3(NCLS),        512, 0, stream>>>(Wb, bb, bl, out);
}